// Round 1
// baseline (4747.181 us; speedup 1.0000x reference)
//
#include <hip/hip_runtime.h>
#include <math.h>

// GRU-RCN: B=8, T=16, Cin=Oh=64, H=W=56, 3x3 SAME convs.
// Strategy: per step, stage1 computes the 5 fused conv planes (Wz,Wr,Wc,Uz,Ur)
// -> z, r*h, wx_c ; stage2 computes conv(r*h, C) + gate combine -> h_new.
// All conv inputs live in zero-padded [58 rows][64 cols] workspace images so
// the inner loop has no boundary masks (constant-immediate-offset loads).

#define B_ 8
#define T_ 16
#define CIN_ 64
#define OH_ 64
#define HH_ 56
#define WW_ 56
#define HW_ (HH_ * WW_)      // 3136
#define PC_ 64               // padded row stride (floats)
#define PR_ 58               // padded rows
#define PIMG_ (PR_ * PC_)    // 3712 floats per padded channel image
#define PCH_ (CIN_ * PIMG_)  // 237568 floats per (b) padded block

__global__ __launch_bounds__(256) void copy_h_pad(const float* __restrict__ src,
                                                  float* __restrict__ dst) {
  int idx = blockIdx.x * 256 + threadIdx.x;
  if (idx >= B_ * CIN_ * HW_) return;
  int p = idx % HW_;
  int c = (idx / HW_) % CIN_;
  int b = idx / (HW_ * CIN_);
  int y = p / WW_, x = p % WW_;
  dst[(size_t)b * PCH_ + (size_t)c * PIMG_ + (y + 1) * PC_ + (x + 1)] = src[idx];
}

__global__ __launch_bounds__(256) void copy_x_pad(const float* __restrict__ x,
                                                  float* __restrict__ dst, int t) {
  int idx = blockIdx.x * 256 + threadIdx.x;
  if (idx >= B_ * CIN_ * HW_) return;
  int p = idx % HW_;
  int c = (idx / HW_) % CIN_;
  int b = idx / (HW_ * CIN_);
  int y = p / WW_, xx = p % WW_;
  dst[(size_t)b * PCH_ + (size_t)c * PIMG_ + (y + 1) * PC_ + (xx + 1)] =
      x[((size_t)(b * T_ + t) * CIN_ + c) * HW_ + p];
}

// stage1: az = conv(x,Wz)+conv(h,Uz); ar = conv(x,Wr)+conv(h,Ur); ac = conv(x,Wc)
// emits: z = sig(az), rh = sig(ar)*h, wxc = ac
// Each wave: one output channel o, 4 output rows x 56 cols (lane = col).
__global__ __launch_bounds__(256) void stage1(
    const float* __restrict__ xpad, const float* __restrict__ hpad,
    const float* __restrict__ W, const float* __restrict__ U,
    float* __restrict__ zb, float* __restrict__ wxcb,
    float* __restrict__ rhpad) {
  const int lane = threadIdx.x & 63;
  const int wave = threadIdx.x >> 6;
  const int rq = blockIdx.x;   // 0..13 (4-row quad)
  const int og = blockIdx.y;   // 0..15 (group of 4 output channels)
  const int b = blockIdx.z;    // 0..7
  const int o = __builtin_amdgcn_readfirstlane(og * 4 + wave);
  const int y0 = rq * 4;
  const int col = lane < 56 ? lane : 55;

  const float* xb = xpad + (size_t)b * PCH_ + (y0 + 1) * PC_ + (col + 1);
  const float* hb = hpad + (size_t)b * PCH_ + (y0 + 1) * PC_ + (col + 1);
  const float* wz = W + (size_t)o * CIN_ * 9;
  const float* wr = W + (size_t)(64 + o) * CIN_ * 9;
  const float* wc = W + (size_t)(128 + o) * CIN_ * 9;
  const float* uz = U + (size_t)o * CIN_ * 9;
  const float* ur = U + (size_t)(64 + o) * CIN_ * 9;

  float az[4] = {0.f, 0.f, 0.f, 0.f};
  float ar[4] = {0.f, 0.f, 0.f, 0.f};
  float ac[4] = {0.f, 0.f, 0.f, 0.f};

#pragma unroll 1
  for (int ci = 0; ci < CIN_; ++ci) {
    float xv[18], hv[18];
#pragma unroll
    for (int j = 0; j < 6; ++j) {
#pragma unroll
      for (int d = 0; d < 3; ++d) {
        xv[j * 3 + d] = xb[(j - 1) * PC_ + (d - 1)];
        hv[j * 3 + d] = hb[(j - 1) * PC_ + (d - 1)];
      }
    }
#pragma unroll
    for (int r = 0; r < 4; ++r) {
#pragma unroll
      for (int ky = 0; ky < 3; ++ky) {
#pragma unroll
        for (int kx = 0; kx < 3; ++kx) {
          const float xt = xv[(r + ky) * 3 + kx];
          const float ht = hv[(r + ky) * 3 + kx];
          const int wi = ky * 3 + kx;
          az[r] = fmaf(xt, wz[wi], az[r]);
          az[r] = fmaf(ht, uz[wi], az[r]);
          ar[r] = fmaf(xt, wr[wi], ar[r]);
          ar[r] = fmaf(ht, ur[wi], ar[r]);
          ac[r] = fmaf(xt, wc[wi], ac[r]);
        }
      }
    }
    xb += PIMG_;
    hb += PIMG_;
    wz += 9; wr += 9; wc += 9; uz += 9; ur += 9;
  }

  if (lane < 56) {
    const int obase = (b * OH_ + o) * HW_ + y0 * WW_ + col;
    const float* hcen =
        hpad + (size_t)b * PCH_ + (size_t)o * PIMG_ + (y0 + 1) * PC_ + (col + 1);
    float* rhw =
        rhpad + (size_t)b * PCH_ + (size_t)o * PIMG_ + (y0 + 1) * PC_ + (col + 1);
#pragma unroll
    for (int r = 0; r < 4; ++r) {
      const float zz = 1.f / (1.f + __expf(-az[r]));
      const float rrr = 1.f / (1.f + __expf(-ar[r]));
      zb[obase + r * WW_] = zz;
      wxcb[obase + r * WW_] = ac[r];
      rhw[r * PC_] = rrr * hcen[r * PC_];
    }
  }
}

// stage2: acc = conv(rh, C); h_new = (1-z)*h + z*tanh(wxc + acc)
__global__ __launch_bounds__(256) void stage2(
    const float* __restrict__ rhpad, const float* __restrict__ Cw,
    const float* __restrict__ zb, const float* __restrict__ wxcb,
    float* __restrict__ hpad, float* __restrict__ out, int t) {
  const int lane = threadIdx.x & 63;
  const int wave = threadIdx.x >> 6;
  const int rq = blockIdx.x;
  const int og = blockIdx.y;
  const int b = blockIdx.z;
  const int o = __builtin_amdgcn_readfirstlane(og * 4 + wave);
  const int y0 = rq * 4;
  const int col = lane < 56 ? lane : 55;

  const float* rb = rhpad + (size_t)b * PCH_ + (y0 + 1) * PC_ + (col + 1);
  const float* w = Cw + (size_t)o * CIN_ * 9;
  float acc[4] = {0.f, 0.f, 0.f, 0.f};

#pragma unroll 1
  for (int ci = 0; ci < CIN_; ++ci) {
    float rv[18];
#pragma unroll
    for (int j = 0; j < 6; ++j) {
#pragma unroll
      for (int d = 0; d < 3; ++d) rv[j * 3 + d] = rb[(j - 1) * PC_ + (d - 1)];
    }
#pragma unroll
    for (int r = 0; r < 4; ++r) {
#pragma unroll
      for (int ky = 0; ky < 3; ++ky) {
#pragma unroll
        for (int kx = 0; kx < 3; ++kx)
          acc[r] = fmaf(rv[(r + ky) * 3 + kx], w[ky * 3 + kx], acc[r]);
      }
    }
    rb += PIMG_;
    w += 9;
  }

  if (lane < 56) {
    const int pix = y0 * WW_ + col;
    const int obase = (b * OH_ + o) * HW_ + pix;
    float* hcen =
        hpad + (size_t)b * PCH_ + (size_t)o * PIMG_ + (y0 + 1) * PC_ + (col + 1);
    float* outp = out + ((size_t)(b * T_ + t) * OH_ + o) * HW_ + pix;
    float* hlast = out + (size_t)B_ * T_ * OH_ * HW_ + obase;
#pragma unroll
    for (int r = 0; r < 4; ++r) {
      const float a = wxcb[obase + r * WW_] + acc[r];
      const float ht = tanhf(a);
      const float zz = zb[obase + r * WW_];
      const float hv = hcen[r * PC_];
      const float hn = (1.f - zz) * hv + zz * ht;
      hcen[r * PC_] = hn;   // running h state (in-place safe: same-thread index)
      outp[r * WW_] = hn;   // outs[b, t]
      if (t == T_ - 1) hlast[r * WW_] = hn;
    }
  }
}

extern "C" void kernel_launch(void* const* d_in, const int* in_sizes, int n_in,
                              void* d_out, int out_size, void* d_ws, size_t ws_size,
                              hipStream_t stream) {
  const float* x = (const float*)d_in[0];
  const float* h = (const float*)d_in[1];
  const float* W = (const float*)d_in[2];
  const float* U = (const float*)d_in[3];
  const float* C = (const float*)d_in[4];
  float* out = (float*)d_out;
  float* ws = (float*)d_ws;

  float* xpad = ws;                                  // [B][64][58][64]
  float* hpad = xpad + (size_t)B_ * PCH_;            // [B][64][58][64]
  float* rhpad = hpad + (size_t)B_ * PCH_;           // [B][64][58][64]
  float* zb = rhpad + (size_t)B_ * PCH_;             // [B][64][56*56]
  float* wxcb = zb + (size_t)B_ * OH_ * HW_;         // [B][64][56*56]

  // zero the padded buffers (borders must be 0; interior rewritten every step)
  hipMemsetAsync(d_ws, 0, (size_t)3 * B_ * PCH_ * sizeof(float), stream);

  const int copyN = B_ * CIN_ * HW_;
  const int copyBlocks = (copyN + 255) / 256;
  copy_h_pad<<<copyBlocks, 256, 0, stream>>>(h, hpad);

  dim3 grid(14, 16, B_);  // (row-quads, o-groups of 4, batch)
  for (int t = 0; t < T_; ++t) {
    copy_x_pad<<<copyBlocks, 256, 0, stream>>>(x, xpad, t);
    stage1<<<grid, 256, 0, stream>>>(xpad, hpad, W, U, zb, wxcb, rhpad);
    stage2<<<grid, 256, 0, stream>>>(rhpad, C, zb, wxcb, hpad, out, t);
  }
}

// Round 2
// 3515.645 us; speedup vs baseline: 1.3503x; 1.3503x over previous
//
#include <hip/hip_runtime.h>
#include <math.h>

// GRU-RCN: B=8, T=16, Cin=Oh=64, H=W=56, 3x3 SAME convs.
// Per step: stage1 = 5 fused conv planes (Wz,Wr,Wc,Uz,Ur) -> z, r*h, wx_c ;
// stage2 = conv(r*h, C) + gate combine -> h_new.
// Conv inputs live in zero-padded [58][64] workspace images (mask-free loads).
// This round: x/h tiles staged in double-buffered LDS via global_load_lds
// (width 16 -> one dwordx4 per wave per ci), 2 output channels per wave.

#define B_ 8
#define T_ 16
#define CIN_ 64
#define OH_ 64
#define HH_ 56
#define WW_ 56
#define HW_ (HH_ * WW_)      // 3136
#define PC_ 64               // padded row stride (floats)
#define PR_ 58               // padded rows
#define PIMG_ (PR_ * PC_)    // 3712 floats per padded channel image
#define PCH_ (CIN_ * PIMG_)  // floats per (b) padded block

__device__ __forceinline__ void gll16(const float* g, float* l) {
  __builtin_amdgcn_global_load_lds(
      (const __attribute__((address_space(1))) void*)g,
      (__attribute__((address_space(3))) void*)l, 16, 0, 0);
}

__global__ __launch_bounds__(256) void copy_h_pad(const float* __restrict__ src,
                                                  float* __restrict__ dst) {
  int idx = blockIdx.x * 256 + threadIdx.x;
  if (idx >= B_ * CIN_ * HW_) return;
  int p = idx % HW_;
  int c = (idx / HW_) % CIN_;
  int b = idx / (HW_ * CIN_);
  int y = p / WW_, x = p % WW_;
  dst[(size_t)b * PCH_ + (size_t)c * PIMG_ + (y + 1) * PC_ + (x + 1)] = src[idx];
}

__global__ __launch_bounds__(256) void copy_x_pad(const float* __restrict__ x,
                                                  float* __restrict__ dst, int t) {
  int idx = blockIdx.x * 256 + threadIdx.x;
  if (idx >= B_ * CIN_ * HW_) return;
  int p = idx % HW_;
  int c = (idx / HW_) % CIN_;
  int b = idx / (HW_ * CIN_);
  int y = p / WW_, xx = p % WW_;
  dst[(size_t)b * PCH_ + (size_t)c * PIMG_ + (y + 1) * PC_ + (xx + 1)] =
      x[((size_t)(b * T_ + t) * CIN_ + c) * HW_ + p];
}

// stage1: az = conv(x,Wz)+conv(h,Uz); ar = conv(x,Wr)+conv(h,Ur); ac = conv(x,Wc)
// emits: z = sig(az), rh = sig(ar)*h, wxc = ac
// Block: 4 waves; wave handles channels {o, o+32}, o = og*4+wave.
// Per ci, block stages x rows y0..y0+7 and h rows y0..y0+7 into LDS
// (1 global_load_lds_dwordx4 per wave: 64 lanes x 16B = 4 rows).
__global__ __launch_bounds__(256) void stage1(
    const float* __restrict__ xpad, const float* __restrict__ hpad,
    const float* __restrict__ W, const float* __restrict__ U,
    float* __restrict__ zb, float* __restrict__ wxcb,
    float* __restrict__ rhpad) {
  __shared__ float lx[2][8][PC_];
  __shared__ float lh[2][8][PC_];
  const int lane = threadIdx.x & 63;
  const int wave = threadIdx.x >> 6;
  const int rq = blockIdx.x;   // 0..13 (4-row quad)
  const int og = blockIdx.y;   // 0..7
  const int b = blockIdx.z;    // 0..7
  const int o = __builtin_amdgcn_readfirstlane(og * 4 + wave);
  const int y0 = rq * 4;
  const int c = lane < 56 ? lane : 55;

  // staging source/dest for this wave (waves 0,1 -> x rows 0-3/4-7; 2,3 -> h)
  const size_t bimg = (size_t)b * PCH_;
  const float* sgx = xpad + bimg + (size_t)(y0 + 4 * (wave & 1)) * PC_ + lane * 4;
  const float* sgh = hpad + bimg + (size_t)(y0 + 4 * (wave & 1)) * PC_ + lane * 4;
  const float* sg = (wave < 2) ? sgx : sgh;
  float* sl0 = (wave < 2) ? &lx[0][4 * (wave & 1)][0] : &lh[0][4 * (wave & 1)][0];

  // weight plane bases: [p][Wz,Wr,Wc,Uz,Ur]
  const float* Wb[2][5];
#pragma unroll
  for (int p = 0; p < 2; ++p) {
    const int oo = o + 32 * p;
    Wb[p][0] = W + (size_t)oo * CIN_ * 9;
    Wb[p][1] = W + (size_t)(64 + oo) * CIN_ * 9;
    Wb[p][2] = W + (size_t)(128 + oo) * CIN_ * 9;
    Wb[p][3] = U + (size_t)oo * CIN_ * 9;
    Wb[p][4] = U + (size_t)(64 + oo) * CIN_ * 9;
  }

  float az[2][4] = {{0.f, 0.f, 0.f, 0.f}, {0.f, 0.f, 0.f, 0.f}};
  float ar[2][4] = {{0.f, 0.f, 0.f, 0.f}, {0.f, 0.f, 0.f, 0.f}};
  float ac[2][4] = {{0.f, 0.f, 0.f, 0.f}, {0.f, 0.f, 0.f, 0.f}};

  gll16(sg, sl0);  // prologue: stage ci=0 into buf 0

#pragma unroll 1
  for (int ci = 0; ci < CIN_; ++ci) {
    // my previous gll retired + all waves' writes visible
    asm volatile("s_waitcnt vmcnt(0)\n\ts_barrier" ::: "memory");
    if (ci + 1 < CIN_)  // issue next tile now; latency hides under FMAs
      gll16(sg + (size_t)(ci + 1) * PIMG_, sl0 + (((ci + 1) & 1) ? 8 * PC_ : 0));

    const int buf = ci & 1;
    float xv[18], hv[18];
#pragma unroll
    for (int j = 0; j < 6; ++j) {
#pragma unroll
      for (int d = 0; d < 3; ++d) {
        xv[j * 3 + d] = lx[buf][j][c + d];
        hv[j * 3 + d] = lh[buf][j][c + d];
      }
    }
#pragma unroll
    for (int p = 0; p < 2; ++p) {
      const float* wz = Wb[p][0] + ci * 9;
      const float* wr = Wb[p][1] + ci * 9;
      const float* wc = Wb[p][2] + ci * 9;
      const float* uz = Wb[p][3] + ci * 9;
      const float* ur = Wb[p][4] + ci * 9;
#pragma unroll
      for (int ky = 0; ky < 3; ++ky) {
#pragma unroll
        for (int kx = 0; kx < 3; ++kx) {
          const int wi = ky * 3 + kx;
          const float wzv = wz[wi], wrv = wr[wi], wcv = wc[wi];
          const float uzv = uz[wi], urv = ur[wi];
#pragma unroll
          for (int r = 0; r < 4; ++r) {
            const float xt = xv[(r + ky) * 3 + kx];
            const float ht = hv[(r + ky) * 3 + kx];
            az[p][r] = fmaf(xt, wzv, az[p][r]);
            az[p][r] = fmaf(ht, uzv, az[p][r]);
            ar[p][r] = fmaf(xt, wrv, ar[p][r]);
            ar[p][r] = fmaf(ht, urv, ar[p][r]);
            ac[p][r] = fmaf(xt, wcv, ac[p][r]);
          }
        }
      }
    }
  }

  if (lane < 56) {
#pragma unroll
    for (int p = 0; p < 2; ++p) {
      const int oo = o + 32 * p;
      const size_t obase = ((size_t)b * OH_ + oo) * HW_ + y0 * WW_ + c;
      const float* hc = hpad + bimg + (size_t)oo * PIMG_ + (y0 + 1) * PC_ + (c + 1);
      float* rhw = rhpad + bimg + (size_t)oo * PIMG_ + (y0 + 1) * PC_ + (c + 1);
#pragma unroll
      for (int r = 0; r < 4; ++r) {
        const float zz = 1.f / (1.f + __expf(-az[p][r]));
        const float rr = 1.f / (1.f + __expf(-ar[p][r]));
        zb[obase + r * WW_] = zz;
        wxcb[obase + r * WW_] = ac[p][r];
        rhw[r * PC_] = rr * hc[r * PC_];
      }
    }
  }
}

// stage2: acc = conv(rh, C); h_new = (1-z)*h + z*tanh(wxc + acc)
__global__ __launch_bounds__(256) void stage2(
    const float* __restrict__ rhpad, const float* __restrict__ Cw,
    const float* __restrict__ zb, const float* __restrict__ wxcb,
    float* __restrict__ hpad, float* __restrict__ out, int t) {
  __shared__ float lr[2][8][PC_];
  const int lane = threadIdx.x & 63;
  const int wave = threadIdx.x >> 6;
  const int rq = blockIdx.x;
  const int og = blockIdx.y;
  const int b = blockIdx.z;
  const int o = __builtin_amdgcn_readfirstlane(og * 4 + wave);
  const int y0 = rq * 4;
  const int c = lane < 56 ? lane : 55;

  const size_t bimg = (size_t)b * PCH_;
  const float* sg = rhpad + bimg + (size_t)(y0 + 4 * (wave & 1)) * PC_ + lane * 4;
  float* sl0 = &lr[0][4 * (wave & 1)][0];

  const float* Cb[2];
  Cb[0] = Cw + (size_t)o * CIN_ * 9;
  Cb[1] = Cw + (size_t)(o + 32) * CIN_ * 9;

  float acc[2][4] = {{0.f, 0.f, 0.f, 0.f}, {0.f, 0.f, 0.f, 0.f}};

  if (wave < 2) gll16(sg, sl0);

#pragma unroll 1
  for (int ci = 0; ci < CIN_; ++ci) {
    asm volatile("s_waitcnt vmcnt(0)\n\ts_barrier" ::: "memory");
    if (wave < 2 && ci + 1 < CIN_)
      gll16(sg + (size_t)(ci + 1) * PIMG_, sl0 + (((ci + 1) & 1) ? 8 * PC_ : 0));

    const int buf = ci & 1;
    float rv[18];
#pragma unroll
    for (int j = 0; j < 6; ++j) {
#pragma unroll
      for (int d = 0; d < 3; ++d) rv[j * 3 + d] = lr[buf][j][c + d];
    }
#pragma unroll
    for (int p = 0; p < 2; ++p) {
      const float* w = Cb[p] + ci * 9;
#pragma unroll
      for (int ky = 0; ky < 3; ++ky) {
#pragma unroll
        for (int kx = 0; kx < 3; ++kx) {
          const float wv = w[ky * 3 + kx];
#pragma unroll
          for (int r = 0; r < 4; ++r)
            acc[p][r] = fmaf(rv[(r + ky) * 3 + kx], wv, acc[p][r]);
        }
      }
    }
  }

  if (lane < 56) {
#pragma unroll
    for (int p = 0; p < 2; ++p) {
      const int oo = o + 32 * p;
      const size_t pix = (size_t)y0 * WW_ + c;
      const size_t obase = ((size_t)b * OH_ + oo) * HW_ + pix;
      float* hc = hpad + bimg + (size_t)oo * PIMG_ + (y0 + 1) * PC_ + (c + 1);
      float* outp = out + ((size_t)(b * T_ + t) * OH_ + oo) * HW_ + pix;
      float* hlast = out + (size_t)B_ * T_ * OH_ * HW_ + obase;
#pragma unroll
      for (int r = 0; r < 4; ++r) {
        const float a = wxcb[obase + r * WW_] + acc[p][r];
        const float ht = tanhf(a);
        const float zz = zb[obase + r * WW_];
        const float hv = hc[r * PC_];
        const float hn = (1.f - zz) * hv + zz * ht;
        hc[r * PC_] = hn;
        outp[r * WW_] = hn;
        if (t == T_ - 1) hlast[r * WW_] = hn;
      }
    }
  }
}

extern "C" void kernel_launch(void* const* d_in, const int* in_sizes, int n_in,
                              void* d_out, int out_size, void* d_ws, size_t ws_size,
                              hipStream_t stream) {
  const float* x = (const float*)d_in[0];
  const float* h = (const float*)d_in[1];
  const float* W = (const float*)d_in[2];
  const float* U = (const float*)d_in[3];
  const float* C = (const float*)d_in[4];
  float* out = (float*)d_out;
  float* ws = (float*)d_ws;

  float* xpad = ws;                              // [B][64][58][64]
  float* hpad = xpad + (size_t)B_ * PCH_;        // [B][64][58][64]
  float* rhpad = hpad + (size_t)B_ * PCH_;       // [B][64][58][64]
  float* zb = rhpad + (size_t)B_ * PCH_;         // [B][64][3136]
  float* wxcb = zb + (size_t)B_ * OH_ * HW_;     // [B][64][3136]

  hipMemsetAsync(d_ws, 0, (size_t)3 * B_ * PCH_ * sizeof(float), stream);

  const int copyN = B_ * CIN_ * HW_;
  const int copyBlocks = (copyN + 255) / 256;
  copy_h_pad<<<copyBlocks, 256, 0, stream>>>(h, hpad);

  dim3 grid(14, 8, B_);  // (row-quads, o-groups of 4 waves x 2ch, batch)
  for (int t = 0; t < T_; ++t) {
    copy_x_pad<<<copyBlocks, 256, 0, stream>>>(x, xpad, t);
    stage1<<<grid, 256, 0, stream>>>(xpad, hpad, W, U, zb, wxcb, rhpad);
    stage2<<<grid, 256, 0, stream>>>(rhpad, C, zb, wxcb, hpad, out, t);
  }
}

// Round 3
// 1353.633 us; speedup vs baseline: 3.5070x; 2.5972x over previous
//
#include <hip/hip_runtime.h>
#include <math.h>

// GRU-RCN via bf16 implicit-GEMM MFMA. B=8,T=16,Cin=Oh=64,H=W=56, 3x3 SAME.
// Layouts:
//   padded images (xpad/hpad/rhpad): bf16 NHWC [b][58 rows][66 cols][64 ci],
//     ci-slices (16B = 8 ci) XOR-swizzled by (col&7) for LDS bank spread.
//   weights wcat: bf16 [plane(ky*3+kx)][o][ci]  (W:192ch, U:128ch, C:64ch)
//   wx: bf16 [b][y][px 0..63][192] ; zb,hstate: f32 [b][y][px 0..63][64]
// Per step: xconv -> convW -> convU(+gates, writes z, r*h) -> convC(+combine).

#define NCI 64
#define PRW 66                 // padded width (cols 0..65; real x -> col x+1)
#define PRH 58                 // padded rows  (real y -> row y+1)
#define PIX (PRW * NCI)        // ushorts per padded row = 4224
#define PIMG (PRH * PIX)       // ushorts per padded image = 244992
#define HL_OFF ((size_t)8 * 16 * 64 * 3136)  // h_last offset in d_out (floats)

typedef __attribute__((ext_vector_type(8))) __bf16 bf16x8;
typedef __attribute__((ext_vector_type(4))) float f32x4;

__device__ __forceinline__ float bf2f(unsigned short u) {
  unsigned int v = ((unsigned int)u) << 16;
  float f;
  __builtin_memcpy(&f, &v, 4);
  return f;
}
__device__ __forceinline__ unsigned short f2bf(float f) {
  unsigned int u;
  __builtin_memcpy(&u, &f, 4);
  u = (u + 0x7FFFu + ((u >> 16) & 1u)) >> 16;  // RNE
  return (unsigned short)u;
}
__device__ __forceinline__ void gll16(const void* g, void* l) {
  __builtin_amdgcn_global_load_lds(
      (const __attribute__((address_space(1))) void*)g,
      (__attribute__((address_space(3))) void*)l, 16, 0, 0);
}

// ---- shared conv core: D[32px x NF*16ch x 4waves] = conv3x3(img, wb) -------
// A-frag: lane l -> A[m=l&15][k=8*(l>>4)+j]; B-frag: lane l -> Wt[n=l&15][k..]
// K = 576 as (ky 3) x (kc 2: 32-ci chunk) x (kx 3). Strip rows y..y+2, cols
// x0..x0+33 staged once in LDS (swizzled); B 1-deep prefetch per (ky,kc).
template <int NF>
__device__ __forceinline__ void conv_core(
    const unsigned short* __restrict__ img,  // batch-b padded image base
    const unsigned short* __restrict__ wb,   // [9][NCH][64]
    const int NCH, const int y, const int x0, const int n0,
    unsigned short* lds, f32x4 (&acc)[2][NF]) {
  const int lane = threadIdx.x & 63;
  const int wv = threadIdx.x >> 6;

  const unsigned short* wrow =
      wb + (size_t)(n0 + (lane & 15)) * 64 + ((lane >> 4) * 8);
#define BPTR(ky, kx, kc, nf) \
  (wrow + (size_t)((ky) * 3 + (kx)) * NCH * 64 + (nf) * 1024 + (kc) * 32)

  bf16x8 bcur[3][NF], bnxt[3][NF];
#pragma unroll
  for (int kx = 0; kx < 3; ++kx)
#pragma unroll
    for (int nf = 0; nf < NF; ++nf)
      bcur[kx][nf] = *(const bf16x8*)BPTR(0, kx, 0, nf);

  // stage strip: 3 rows x 34 px x 128B = 13056B; per row 4x1KB + 256B
#pragma unroll
  for (int i = wv; i < 15; i += 4) {
    const int r = i / 5, k = i % 5;
    const unsigned short* g =
        img + (size_t)(y + r) * PIX + x0 * 64 + k * 512 + lane * 8;
    unsigned short* l = lds + r * 2176 + k * 512;
    if (k < 4 || lane < 16) gll16(g, l);
  }
  asm volatile("s_waitcnt vmcnt(0)" ::: "memory");
  __syncthreads();

#pragma unroll 1
  for (int kk = 0; kk < 6; ++kk) {
    const int ky = kk >> 1, kc = kk & 1;
    if (kk < 5) {
      const int ky2 = (kk + 1) >> 1, kc2 = (kk + 1) & 1;
#pragma unroll
      for (int kx = 0; kx < 3; ++kx)
#pragma unroll
        for (int nf = 0; nf < NF; ++nf)
          bnxt[kx][nf] = *(const bf16x8*)BPTR(ky2, kx, kc2, nf);
    }
    bf16x8 afr[2][3];
#pragma unroll
    for (int mf = 0; mf < 2; ++mf)
#pragma unroll
      for (int kx = 0; kx < 3; ++kx) {
        const int p = mf * 16 + (lane & 15) + kx;
        const int sl = (kc * 4 + (lane >> 4)) ^ (p & 7);
        afr[mf][kx] = *(const bf16x8*)(lds + (ky * 34 + p) * 64 + sl * 8);
      }
#pragma unroll
    for (int kx = 0; kx < 3; ++kx)
#pragma unroll
      for (int mf = 0; mf < 2; ++mf)
#pragma unroll
        for (int nf = 0; nf < NF; ++nf)
          acc[mf][nf] = __builtin_amdgcn_mfma_f32_16x16x32_bf16(
              afr[mf][kx], bcur[kx][nf], acc[mf][nf], 0, 0, 0);
#pragma unroll
    for (int kx = 0; kx < 3; ++kx)
#pragma unroll
      for (int nf = 0; nf < NF; ++nf)
        bcur[kx][nf] = bnxt[kx][nf];
  }
#undef BPTR
}

// ---- weight repack: [o][ci][3][3] f32 -> wcat bf16 [plane][o][ci] ----------
__global__ __launch_bounds__(256) void wprep_k(const float* __restrict__ W,
                                               const float* __restrict__ U,
                                               const float* __restrict__ C,
                                               unsigned short* __restrict__ wcat) {
  int i = blockIdx.x * 256 + threadIdx.x;
  if (i >= 221184) return;
  float v;
  if (i < 110592) {  // W: [9][192][64]
    int plane = i / 12288, rem = i % 12288, o = rem / 64, ci = rem % 64;
    v = W[(size_t)(o * 64 + ci) * 9 + plane];
  } else if (i < 184320) {  // U: [9][128][64]
    int j = i - 110592;
    int plane = j / 8192, rem = j % 8192, o = rem / 64, ci = rem % 64;
    v = U[(size_t)(o * 64 + ci) * 9 + plane];
  } else {  // C: [9][64][64]
    int j = i - 184320;
    int plane = j / 4096, rem = j % 4096, o = rem / 64, ci = rem % 64;
    v = C[(size_t)(o * 64 + ci) * 9 + plane];
  }
  wcat[i] = f2bf(v);
}

// ---- h init: NCHW f32 -> hpad bf16 (swizzled) + hstate f32 NHWC -----------
__global__ __launch_bounds__(256) void hinit_k(const float* __restrict__ h,
                                               unsigned short* __restrict__ hpad,
                                               float* __restrict__ hstate) {
  __shared__ float t[64][57];
  const int y = blockIdx.x, b = blockIdx.y;
  const int tid = threadIdx.x;
  for (int i = tid; i < 64 * 56; i += 256) {
    int ci = i / 56, xx = i % 56;
    t[ci][xx] = h[((size_t)(b * 64) + ci) * 3136 + y * 56 + xx];
  }
  __syncthreads();
  const size_t pb = (size_t)b * PIMG + (size_t)(y + 1) * PIX;
  const size_t sb = ((size_t)(b * 56) + y) * 64;
  for (int i = tid; i < 56 * 64; i += 256) {
    int px = i / 64, ci = i % 64;
    float v = t[ci][px];
    int gx = px + 1;
    hpad[pb + gx * 64 + (((ci >> 3) ^ (gx & 7)) << 3) + (ci & 7)] = f2bf(v);
    hstate[(sb + px) * 64 + ci] = v;
  }
}

// ---- x_t: NCHW f32 -> xpad bf16 (swizzled) ---------------------------------
__global__ __launch_bounds__(256) void xconv_k(const float* __restrict__ x,
                                               unsigned short* __restrict__ xpad,
                                               int t) {
  __shared__ float tt[64][57];
  const int y = blockIdx.x, b = blockIdx.y;
  const int tid = threadIdx.x;
  for (int i = tid; i < 64 * 56; i += 256) {
    int ci = i / 56, xx = i % 56;
    tt[ci][xx] = x[((size_t)(b * 16 + t) * 64 + ci) * 3136 + y * 56 + xx];
  }
  __syncthreads();
  const size_t pb = (size_t)b * PIMG + (size_t)(y + 1) * PIX;
  for (int i = tid; i < 56 * 64; i += 256) {
    int px = i / 64, ci = i % 64;
    int gx = px + 1;
    xpad[pb + gx * 64 + (((ci >> 3) ^ (gx & 7)) << 3) + (ci & 7)] =
        f2bf(tt[ci][px]);
  }
}

// ---- convW: wx = conv(x, W[192]) -> bf16 [b][y][px][192] -------------------
__global__ __launch_bounds__(256) void convW_k(
    const unsigned short* __restrict__ xpad,
    const unsigned short* __restrict__ wcat,
    unsigned short* __restrict__ wx) {
  __shared__ unsigned short lds[3 * 34 * 64];
  const int x0 = blockIdx.x * 32, y = blockIdx.y, b = blockIdx.z;
  const int lane = threadIdx.x & 63;
  const int n0 = __builtin_amdgcn_readfirstlane((threadIdx.x >> 6) * 48);
  f32x4 acc[2][3];
#pragma unroll
  for (int mf = 0; mf < 2; ++mf)
#pragma unroll
    for (int nf = 0; nf < 3; ++nf) acc[mf][nf] = (f32x4){0.f, 0.f, 0.f, 0.f};
  conv_core<3>(xpad + (size_t)b * PIMG, wcat, 192, y, x0, n0, lds, acc);

  const size_t rowb = ((size_t)(b * 56) + y) * 64;
#pragma unroll
  for (int mf = 0; mf < 2; ++mf)
#pragma unroll
    for (int nf = 0; nf < 3; ++nf) {
      const int n = n0 + nf * 16 + (lane & 15);
#pragma unroll
      for (int r = 0; r < 4; ++r) {
        const int px = x0 + mf * 16 + 4 * (lane >> 4) + r;
        wx[(rowb + px) * 192 + n] = f2bf(acc[mf][nf][r]);
      }
    }
}

// ---- convU: uh = conv(h, U[128]); z=sig(wx_z+uh_z); rh=sig(wx_r+uh_r)*h ----
__global__ __launch_bounds__(256) void convU_k(
    const unsigned short* __restrict__ hpad,
    const unsigned short* __restrict__ ucat,
    const unsigned short* __restrict__ wx, const float* __restrict__ hstate,
    float* __restrict__ zb, unsigned short* __restrict__ rhpad) {
  __shared__ unsigned short lds[3 * 34 * 64];
  const int x0 = blockIdx.x * 32, y = blockIdx.y, b = blockIdx.z;
  const int lane = threadIdx.x & 63;
  const int n0 = __builtin_amdgcn_readfirstlane((threadIdx.x >> 6) * 32);
  f32x4 acc[2][2];
#pragma unroll
  for (int mf = 0; mf < 2; ++mf)
#pragma unroll
    for (int nf = 0; nf < 2; ++nf) acc[mf][nf] = (f32x4){0.f, 0.f, 0.f, 0.f};
  conv_core<2>(hpad + (size_t)b * PIMG, ucat, 128, y, x0, n0, lds, acc);

  const size_t rowb = ((size_t)(b * 56) + y) * 64;
#pragma unroll
  for (int mf = 0; mf < 2; ++mf)
#pragma unroll
    for (int nf = 0; nf < 2; ++nf) {
      const int n = n0 + nf * 16 + (lane & 15);
#pragma unroll
      for (int r = 0; r < 4; ++r) {
        const int px = x0 + mf * 16 + 4 * (lane >> 4) + r;
        if (px < 56) {
          float a = bf2f(wx[(rowb + px) * 192 + n]) + acc[mf][nf][r];
          float s = 1.f / (1.f + __expf(-a));
          if (n < 64) {
            zb[(rowb + px) * 64 + n] = s;
          } else {
            const int ci = n - 64;
            float rh = s * hstate[(rowb + px) * 64 + ci];
            const int gx = px + 1;
            rhpad[(size_t)b * PIMG + (size_t)(y + 1) * PIX + gx * 64 +
                  (((ci >> 3) ^ (gx & 7)) << 3) + (ci & 7)] = f2bf(rh);
          }
        }
      }
    }
}

// ---- convC: cc = conv(rh, C[64]); h_new = (1-z)h + z tanh(wx_c + cc) -------
__global__ __launch_bounds__(256) void convC_k(
    const unsigned short* __restrict__ rhpad,
    const unsigned short* __restrict__ ccat,
    const unsigned short* __restrict__ wx, const float* __restrict__ zb,
    float* __restrict__ hstate, unsigned short* __restrict__ hpad,
    float* __restrict__ out, int t) {
  __shared__ unsigned short lds[3 * 34 * 64];
  __shared__ float ldt[4][16][33];
  const int x0 = blockIdx.x * 32, y = blockIdx.y, b = blockIdx.z;
  const int lane = threadIdx.x & 63;
  const int wv = threadIdx.x >> 6;
  const int n0 = __builtin_amdgcn_readfirstlane(wv * 16);
  f32x4 acc[2][1];
  acc[0][0] = (f32x4){0.f, 0.f, 0.f, 0.f};
  acc[1][0] = (f32x4){0.f, 0.f, 0.f, 0.f};
  conv_core<1>(rhpad + (size_t)b * PIMG, ccat, 64, y, x0, n0, lds, acc);

  const size_t rowb = ((size_t)(b * 56) + y) * 64;
  const int n = n0 + (lane & 15);
#pragma unroll
  for (int mf = 0; mf < 2; ++mf)
#pragma unroll
    for (int r = 0; r < 4; ++r) {
      const int px = x0 + mf * 16 + 4 * (lane >> 4) + r;
      if (px < 56) {
        float a = bf2f(wx[(rowb + px) * 192 + 128 + n]) + acc[mf][0][r];
        float htil = tanhf(a);
        float z = zb[(rowb + px) * 64 + n];
        float ho = hstate[(rowb + px) * 64 + n];
        float hn = fmaf(z, htil - ho, ho);
        hstate[(rowb + px) * 64 + n] = hn;
        const int gx = px + 1;
        hpad[(size_t)b * PIMG + (size_t)(y + 1) * PIX + gx * 64 +
             (((n >> 3) ^ (gx & 7)) << 3) + (n & 7)] = f2bf(hn);
        ldt[wv][lane & 15][mf * 16 + 4 * (lane >> 4) + r] = hn;
      }
    }
  __syncthreads();
  const int xl = lane & 31;
  const int px = x0 + xl;
  if (px < 56) {
#pragma unroll
    for (int cc = 0; cc < 8; ++cc) {
      const int ch = (lane >> 5) * 8 + cc;
      float v = ldt[wv][ch][xl];
      const size_t oidx =
          (((size_t)(b * 16 + t)) * 64 + n0 + ch) * 3136 + y * 56 + px;
      out[oidx] = v;
      if (t == 15)
        out[HL_OFF + ((size_t)(b * 64) + n0 + ch) * 3136 + y * 56 + px] = v;
    }
  }
}

extern "C" void kernel_launch(void* const* d_in, const int* in_sizes, int n_in,
                              void* d_out, int out_size, void* d_ws,
                              size_t ws_size, hipStream_t stream) {
  const float* x = (const float*)d_in[0];
  const float* h = (const float*)d_in[1];
  const float* W = (const float*)d_in[2];
  const float* U = (const float*)d_in[3];
  const float* C = (const float*)d_in[4];
  float* out = (float*)d_out;

  unsigned short* ws_u = (unsigned short*)d_ws;
  unsigned short* xpad = ws_u;                       // 1,959,936 u16
  unsigned short* hpad = xpad + (size_t)8 * PIMG;    // 1,959,936
  unsigned short* rhpad = hpad + (size_t)8 * PIMG;   // 1,959,936
  unsigned short* wcat = rhpad + (size_t)8 * PIMG;   // 221,184
  unsigned short* wx = wcat + 221184;                // 5,505,024
  float* zb = (float*)(wx + 5505024);                // 1,835,008 f32
  float* hstate = zb + 1835008;                      // 1,835,008 f32

  // zero the 3 padded images (borders must be 0; interiors rewritten)
  hipMemsetAsync(d_ws, 0, (size_t)3 * 8 * PIMG * sizeof(unsigned short),
                 stream);
  wprep_k<<<864, 256, 0, stream>>>(W, U, C, wcat);
  hinit_k<<<dim3(56, 8), 256, 0, stream>>>(h, hpad, hstate);

  dim3 cgrid(2, 56, 8);
  for (int t = 0; t < 16; ++t) {
    xconv_k<<<dim3(56, 8), 256, 0, stream>>>(x, xpad, t);
    convW_k<<<cgrid, 256, 0, stream>>>(xpad, wcat, wx);
    convU_k<<<cgrid, 256, 0, stream>>>(hpad, wcat + 110592, wx, hstate, zb,
                                       rhpad);
    convC_k<<<cgrid, 256, 0, stream>>>(rhpad, wcat + 184320, wx, zb, hstate,
                                       hpad, out, t);
  }
}